// Round 13
// baseline (372.322 us; speedup 1.0000x reference)
//
#include <hip/hip_runtime.h>
#include <math.h>
#include <float.h>

// Problem constants (match reference)
#define BATCH 4
#define KCLS 16
#define NSRC 4096
#define NTGT 16384

// bucket grid over x in [-4,4]: 128 strips of width 1/16 (exact pow2 consts)
#define NB 128
#define XMIN (-4.0f)
#define BW 0.0625f
#define INVW 16.0f
// frozen-expanded d2 vs exact d2 differ by <= ~2e-5 abs; 1e-3 is ample slack
#define MARGIN 1e-3f

// Prep: one block per batch. Bucket-sort sources by x strip; original index
// packed into .w (bucket-internal order is racy/arbitrary — harmless, the
// scan's (d2, idx) lexicographic min is order-independent).
__global__ __launch_bounds__(512) void prep_kernel(
    const float* __restrict__ source_pos,   // [B, 3, NS]
    float4* __restrict__ srt4,              // [B*NS] (x,y,z,orig_idx_bits)
    int* __restrict__ bstart)               // [B*(NB+1)] bucket offsets
{
    __shared__ int hist[NB];
    __shared__ int scanb[NB + 1];
    __shared__ int cursor[NB];

    int b = blockIdx.x;
    int tid = threadIdx.x;
    const float* sx = source_pos + (size_t)b * 3 * NSRC;
    const float* sy = sx + NSRC;
    const float* sz = sx + 2 * NSRC;

    if (tid < NB) hist[tid] = 0;
    __syncthreads();

    float xs[8], ys[8], zs[8];
    int bins[8];
#pragma unroll
    for (int j = 0; j < 8; ++j) {
        int s = tid + j * 512;              // 512*8 = 4096
        float x = sx[s]; xs[j] = x; ys[j] = sy[s]; zs[j] = sz[s];
        float v = (x - XMIN) * INVW;
        int bin = (int)fminf(fmaxf(v, 0.0f), (float)(NB - 1));  // clamp tails
        bins[j] = bin;
        atomicAdd(&hist[bin], 1);
    }
    __syncthreads();

    // exclusive prefix (Kogge-Stone inclusive on scanb[1..NB])
    if (tid < NB) scanb[tid + 1] = hist[tid];
    if (tid == 0) scanb[0] = 0;
    __syncthreads();
    for (int off = 1; off < NB; off <<= 1) {
        int v = 0;
        if (tid < NB && tid >= off) v = scanb[tid + 1 - off];
        __syncthreads();
        if (tid < NB && tid >= off) scanb[tid + 1] += v;
        __syncthreads();
    }
    if (tid < NB + 1) bstart[b * (NB + 1) + tid] = scanb[tid];
    if (tid < NB) cursor[tid] = scanb[tid];
    __syncthreads();

    float4* dst = srt4 + (size_t)b * NSRC;
#pragma unroll
    for (int j = 0; j < 8; ++j) {
        int s = tid + j * 512;
        int pos = atomicAdd(&cursor[bins[j]], 1);
        dst[pos] = make_float4(xs[j], ys[j], zs[j], __int_as_float(s));
    }
}

// Scan: 256 threads = 64 targets x 4 strided sub-scanners. Ring-expand x
// strips from the home bucket; stop a side when strip-edge dx^2 > best+MARGIN.
// Bit-exact np numerics (verified absmax=0.0 R5-R12):
//   ss/tt: squares rounded individually, then sequential sum
//   dot  : rn(tx*sx); fma(ty,sy,.); fma(tz,sz,.)
//   d2   : fma(-2, dot, rn(tt+ss))
// Tie-break: explicit (d2, orig_idx) lexicographic == np.argmin first-index.
__global__ __launch_bounds__(256) void scan_kernel(
    const float4* __restrict__ srt4,        // [B*NS] bucket-sorted
    const int* __restrict__ bstart,         // [B*(NB+1)]
    const float* __restrict__ target_pos,   // [B, 3, NT]
    const float* __restrict__ sem_logits,   // [B, K, NS]
    float* __restrict__ out)                // [B*NT]
{
    __shared__ int lbs[NB + 1];
    __shared__ float smin[4 * 64];
    __shared__ int sidxs[4 * 64];

    int tid = threadIdx.x;
    int j = tid & 63;                       // target within block
    int k = tid >> 6;                       // sub-scanner 0..3

    int b = blockIdx.x >> 8;                // 256 blocks per batch
    int t = ((blockIdx.x & 255) << 6) + j;

    if (tid < NB + 1) lbs[tid] = bstart[b * (NB + 1) + tid];
    __syncthreads();

    const float* tp = target_pos + (size_t)b * 3 * NTGT;
    float tx = tp[t], ty = tp[NTGT + t], tz = tp[2 * NTGT + t];
    float tt = __fadd_rn(__fadd_rn(__fmul_rn(tx, tx), __fmul_rn(ty, ty)),
                         __fmul_rn(tz, tz));

    const float4* S = srt4 + (size_t)b * NSRC;

    float bestf = FLT_MAX;
    int bidx = 0x7FFFFFFF;

    float v = (tx - XMIN) * INVW;
    int hb = (int)fminf(fmaxf(v, 0.0f), (float)(NB - 1));

    int lo = hb, hi = hb;
    int bk = hb;                            // first bucket = home
    while (true) {
        // scan bucket bk with stride 4, offset k
        int s0 = lbs[bk], s1 = lbs[bk + 1];
        for (int i = s0 + k; i < s1; i += 4) {
            float4 f = S[i];
            int idx = __float_as_int(f.w);
            float ss = __fadd_rn(__fadd_rn(__fmul_rn(f.x, f.x),
                                           __fmul_rn(f.y, f.y)),
                                 __fmul_rn(f.z, f.z));
            float acc = __fmul_rn(tx, f.x);
            acc = __fmaf_rn(ty, f.y, acc);
            acc = __fmaf_rn(tz, f.z, acc);
            float d2 = __fmaf_rn(-2.0f, acc, __fadd_rn(tt, ss));
            if (d2 < bestf || (d2 == bestf && idx < bidx)) {
                bestf = d2; bidx = idx;
            }
        }
        // pick next bucket (nearer side first); stop when both sides pruned
        float dl = (lo > 0) ? (tx - (XMIN + (float)lo * BW)) : FLT_MAX;
        float dr = (hi < NB - 1) ? ((XMIN + (float)(hi + 1) * BW) - tx) : FLT_MAX;
        float bound = bestf + MARGIN;
        bool canL = (lo > 0) && (dl * dl <= bound);
        bool canR = (hi < NB - 1) && (dr * dr <= bound);
        if (!canL && !canR) break;
        bk = (canL && (!canR || dl <= dr)) ? --lo : ++hi;
    }

    smin[k * 64 + j] = bestf;
    sidxs[k * 64 + j] = bidx;
    __syncthreads();

    if (k == 0) {
        float m = bestf; int mi = bidx;
#pragma unroll
        for (int kk = 1; kk < 4; ++kk) {
            float mj = smin[kk * 64 + j];
            int ij = sidxs[kk * 64 + j];
            if (mj < m || (mj == m && ij < mi)) { m = mj; mi = ij; }
        }
        // lazy gate at winning index: max over K logits, then sigmoid
        const float* lg = sem_logits + (size_t)b * KCLS * NSRC + mi;
        float mm = lg[0];
#pragma unroll
        for (int kk = 1; kk < KCLS; ++kk) mm = fmaxf(mm, lg[(size_t)kk * NSRC]);
        out[(size_t)b * NTGT + t] = 1.0f / (1.0f + expf(-mm));
    }
}

extern "C" void kernel_launch(void* const* d_in, const int* in_sizes, int n_in,
                              void* d_out, int out_size, void* d_ws, size_t ws_size,
                              hipStream_t stream) {
    const float* sem_logits = (const float*)d_in[0];   // [B,K,NS] fp32
    const float* source_pos = (const float*)d_in[1];   // [B,3,NS] fp32
    const float* target_pos = (const float*)d_in[2];   // [B,3,NT] fp32
    float* out = (float*)d_out;                        // [B,NT,1] fp32

    // ws layout: srt4 (B*NS float4 = 256 KB) | bstart (B*(NB+1) ints ~2 KB)
    float4* srt4 = (float4*)d_ws;
    int* bstart = (int*)((char*)d_ws + sizeof(float4) * BATCH * NSRC);

    prep_kernel<<<BATCH, 512, 0, stream>>>(source_pos, srt4, bstart);
    scan_kernel<<<BATCH * (NTGT / 64), 256, 0, stream>>>(
        srt4, bstart, target_pos, sem_logits, out);
}

// Round 14
// 262.565 us; speedup vs baseline: 1.4180x; 1.4180x over previous
//
#include <hip/hip_runtime.h>
#include <math.h>
#include <float.h>

// Problem constants (match reference)
#define BATCH 4
#define KCLS 16
#define NSRC 4096
#define NTGT 16384

// bucket grid over x in [-4,4]: 128 strips of width 1/16 (clamped tails)
#define NB 128
#define XMIN (-4.0f)
#define INVW 16.0f
// frozen-expanded d2 vs exact d2 differ by <= ~3e-5 abs; 1e-3 is ample slack
#define MARGIN 1e-3f

// Fused prep: 8 blocks of 1024. Blocks 0-3: bucket-sort sources of batch b
// (store (x,y,z,frozen ss) + original index side array + bucket offsets).
// Blocks 4-7: bucket-sort targets of batch b (store (x,y,z,idx_bits)).
// Bucket-internal order is racy/arbitrary — harmless: the scan's (d2, idx)
// lexicographic min is order-independent.
__global__ __launch_bounds__(1024) void prep_kernel(
    const float* __restrict__ source_pos,   // [B, 3, NS]
    const float* __restrict__ target_pos,   // [B, 3, NT]
    float4* __restrict__ srt4,              // [B*NS] (x,y,z,ss)
    int* __restrict__ sidxg,                // [B*NS] original source index
    int* __restrict__ bstart,               // [B*(NB+1)] source bucket offsets
    float4* __restrict__ tgt4)              // [B*NT] (x,y,z,orig_idx_bits)
{
    __shared__ int hist[NB];
    __shared__ int scanb[NB + 1];
    __shared__ int cursor[NB];

    int tid = threadIdx.x;
    int bid = blockIdx.x;                   // 0..7
    int b = bid & 3;
    bool isSrc = bid < 4;
    int N = isSrc ? NSRC : NTGT;
    int per = N / 1024;                     // 4 or 16

    const float* px = (isSrc ? source_pos : target_pos) + (size_t)b * 3 * N;
    const float* py = px + N;
    const float* pz = px + 2 * N;

    if (tid < NB) hist[tid] = 0;
    __syncthreads();

    float xs[16], ys[16], zs[16];
    int bins[16];
    for (int j = 0; j < per; ++j) {
        int s = tid + j * 1024;
        float x = px[s]; xs[j] = x; ys[j] = py[s]; zs[j] = pz[s];
        float v = (x - XMIN) * INVW;
        int bin = (int)fminf(fmaxf(v, 0.0f), (float)(NB - 1));
        bins[j] = bin;
        atomicAdd(&hist[bin], 1);
    }
    __syncthreads();

    // exclusive prefix (Kogge-Stone inclusive on scanb[1..NB])
    if (tid < NB) scanb[tid + 1] = hist[tid];
    if (tid == 0) scanb[0] = 0;
    __syncthreads();
    for (int off = 1; off < NB; off <<= 1) {
        int v = 0;
        if (tid < NB && tid >= off) v = scanb[tid + 1 - off];
        __syncthreads();
        if (tid < NB && tid >= off) scanb[tid + 1] += v;
        __syncthreads();
    }
    if (isSrc && tid < NB + 1) bstart[b * (NB + 1) + tid] = scanb[tid];
    if (tid < NB) cursor[tid] = scanb[tid];
    __syncthreads();

    for (int j = 0; j < per; ++j) {
        int s = tid + j * 1024;
        int pos = atomicAdd(&cursor[bins[j]], 1);
        if (isSrc) {
            float x = xs[j], y = ys[j], z = zs[j];
            // frozen numpy order: squares rounded individually, sequential sum
            float ss = __fadd_rn(__fadd_rn(__fmul_rn(x, x), __fmul_rn(y, y)),
                                 __fmul_rn(z, z));
            srt4[(size_t)b * NSRC + pos] = make_float4(x, y, z, ss);
            sidxg[(size_t)b * NSRC + pos] = s;
        } else {
            tgt4[(size_t)b * NTGT + pos] =
                make_float4(xs[j], ys[j], zs[j], __int_as_float(s));
        }
    }
}

// Scan: one wave (64 thr) per block; wave owns 64 x-SORTED targets (1/lane).
// Wave-uniform window over x-sorted sources, scanned in 64-source chunks:
// coalesced stage into LDS, then broadcast stage[i] reads — R9's proven
// inner pattern (no divergence, no bank conflicts).
// Bit-exact np numerics (verified absmax=0.0 R5-R13):
//   ss/tt: squares rounded individually, then sequential sum
//   dot  : rn(tx*sx); fma(ty,sy,.); fma(tz,sz,.)
//   d2   : fma(-2, dot, rn(tt+ss))
// Soundness of prune: any source able to beat/tie the final frozen best has
// exact d2 <= best1 + 3e-5 < best1 + MARGIN  =>  |x_s - x_t| <= r.
// Tie-break: (d2, orig_idx) lexicographic == np.argmin first-index.
__global__ __launch_bounds__(64) void scan_kernel(
    const float4* __restrict__ srt4,        // [B*NS] sorted (x,y,z,ss)
    const int* __restrict__ sidxg,          // [B*NS] original indices
    const int* __restrict__ bstart,         // [B*(NB+1)]
    const float4* __restrict__ tgt4,        // [B*NT] sorted (x,y,z,idx)
    const float* __restrict__ sem_logits,   // [B, K, NS]
    float* __restrict__ out)                // [B*NT]
{
    __shared__ float4 stage[64];
    __shared__ int istage[64];

    int lane = threadIdx.x;
    int b = blockIdx.x >> 8;                // 256 blocks per batch
    int wbase = (blockIdx.x & 255) << 6;

    const int* lbs = bstart + b * (NB + 1);
    const float4* S = srt4 + (size_t)b * NSRC;
    const int* SI = sidxg + (size_t)b * NSRC;

    float4 T = tgt4[(size_t)b * NTGT + wbase + lane];
    float tx = T.x, ty = T.y, tz = T.z;
    int torig = __float_as_int(T.w);
    float tt = __fadd_rn(__fadd_rn(__fmul_rn(tx, tx), __fmul_rn(ty, ty)),
                         __fmul_rn(tz, tz));

    float v = (tx - XMIN) * INVW;
    int hb = (int)fminf(fmaxf(v, 0.0f), (float)(NB - 1));

    // wave min/max of home buckets (targets x-sorted -> tight span)
    int lo = hb, hi = hb;
#pragma unroll
    for (int m = 1; m < 64; m <<= 1) {
        lo = min(lo, __shfl_xor(lo, m));
        hi = max(hi, __shfl_xor(hi, m));
    }
    lo = __builtin_amdgcn_readfirstlane(lo);
    hi = __builtin_amdgcn_readfirstlane(hi);
    // rare: extend until the phase-1 window holds at least one source
    while (lbs[hi + 1] - lbs[lo] == 0) {
        if (lo > 0) --lo;
        if (hi < NB - 1) ++hi;
    }

    float best = FLT_MAX;
    int bidx = 0x7FFFFFFF;

    auto scan_range = [&](int s0, int s1) {
        for (int c = s0; c < s1; c += 64) {
            int n = s1 - c; if (n > 64) n = 64;
            __syncthreads();                // prior chunk's readers done
            if (lane < n) {
                stage[lane] = S[c + lane];  // coalesced
                istage[lane] = SI[c + lane];
            }
            __syncthreads();
            for (int i = 0; i < n; ++i) {   // uniform -> LDS broadcast
                float4 f = stage[i];
                int idx = istage[i];
                float acc = __fmul_rn(tx, f.x);
                acc = __fmaf_rn(ty, f.y, acc);
                acc = __fmaf_rn(tz, f.z, acc);
                float d2 = __fmaf_rn(-2.0f, acc, __fadd_rn(tt, f.w));
                bool lt = d2 < best;
                bool tie = (d2 == best) && (idx < bidx);
                if (lt) best = d2;
                if (lt || tie) bidx = idx;
            }
        }
    };

    // phase 1: home span
    scan_range(lbs[lo], lbs[hi + 1]);

    // phase 2: radius from phase-1 bound (monotone -> no re-check needed)
    float r = __fmul_rn(sqrtf(__fadd_rn(best, MARGIN)), 1.0001f);
    float vl = (tx - r - XMIN) * INVW;
    float vr = (tx + r - XMIN) * INVW;
    int wlo = (int)fminf(fmaxf(vl, 0.0f), (float)(NB - 1));
    int whi = (int)fminf(fmaxf(vr, 0.0f), (float)(NB - 1));
#pragma unroll
    for (int m = 1; m < 64; m <<= 1) {
        wlo = min(wlo, __shfl_xor(wlo, m));
        whi = max(whi, __shfl_xor(whi, m));
    }
    wlo = __builtin_amdgcn_readfirstlane(wlo);
    whi = __builtin_amdgcn_readfirstlane(whi);
    if (wlo < lo) scan_range(lbs[wlo], lbs[lo]);
    if (whi > hi) scan_range(lbs[hi + 1], lbs[whi + 1]);

    // lazy gate at winning index: max over K logits, then sigmoid
    const float* lg = sem_logits + (size_t)b * KCLS * NSRC + bidx;
    float mm = lg[0];
#pragma unroll
    for (int k = 1; k < KCLS; ++k) mm = fmaxf(mm, lg[(size_t)k * NSRC]);
    out[(size_t)b * NTGT + torig] = 1.0f / (1.0f + expf(-mm));
}

extern "C" void kernel_launch(void* const* d_in, const int* in_sizes, int n_in,
                              void* d_out, int out_size, void* d_ws, size_t ws_size,
                              hipStream_t stream) {
    const float* sem_logits = (const float*)d_in[0];   // [B,K,NS] fp32
    const float* source_pos = (const float*)d_in[1];   // [B,3,NS] fp32
    const float* target_pos = (const float*)d_in[2];   // [B,3,NT] fp32
    float* out = (float*)d_out;                        // [B,NT,1] fp32

    // ws layout: srt4 256 KB | tgt4 1 MB | sidxg 64 KB | bstart ~2 KB
    char* w = (char*)d_ws;
    float4* srt4 = (float4*)w;                          w += sizeof(float4) * BATCH * NSRC;
    float4* tgt4 = (float4*)w;                          w += sizeof(float4) * BATCH * NTGT;
    int* sidxg = (int*)w;                               w += sizeof(int) * BATCH * NSRC;
    int* bstart = (int*)w;

    prep_kernel<<<8, 1024, 0, stream>>>(source_pos, target_pos,
                                        srt4, sidxg, bstart, tgt4);
    scan_kernel<<<BATCH * (NTGT / 64), 64, 0, stream>>>(
        srt4, sidxg, bstart, tgt4, sem_logits, out);
}